// Round 12
// baseline (6507.867 us; speedup 1.0000x reference)
//
#include <hip/hip_runtime.h>
#include <math.h>

// Problem constants
#define B 2048
#define T 128
#define H 512
#define NC 3
#define NO 5
#define G3H 1536
#define BHE ((size_t)B * H)

typedef _Float16 half8 __attribute__((ext_vector_type(8)));
typedef float float4v __attribute__((ext_vector_type(4)));

#define LO_SCALE 1024.0f
#define INV_LO (1.0f / 1024.0f)
#define F16_MIN_NORM 6.103515625e-05f

__device__ __forceinline__ float sigmoidf_(float x) { return 1.0f / (1.0f + __expf(-x)); }

// Split fp32 -> (hi, lo*1024) f16 pair; hi zeroed in subnormal range (flush safety).
__device__ __forceinline__ void split_f16(float a, _Float16* hi, _Float16* lo) {
    _Float16 h = (_Float16)a;
    if (fabsf(a) < F16_MIN_NORM) h = (_Float16)0.0f;
    *hi = h;
    *lo = (_Float16)((a - (float)h) * LO_SCALE);
}

// element (row,k) of a 512-col matrix stored at row*512 + swzk(row,k):
// 16B chunk c=(k>>3)&7 lives in slot c ^ (row&7)  (LDS-conflict-free fragments)
__device__ __forceinline__ int swzk(int row, int k) {
    return (k & ~63) | ((((k >> 3) & 7) ^ (row & 7)) << 3) | (k & 7);
}
__device__ __forceinline__ size_t hidx(int row, int k) {
    return (size_t)row * H + swzk(row, k);
}

// async 16B global->LDS (wave-uniform LDS base; lane lands at base + lane*16B)
__device__ __forceinline__ void stage16(const _Float16* gp, _Float16* lp) {
    __builtin_amdgcn_global_load_lds(
        (const __attribute__((address_space(1))) unsigned int*)gp,
        (__attribute__((address_space(3))) unsigned int*)lp,
        16, 0, 0);
}

// 80KB smem carve (macro arithmetic — pointer ARRAYS into LDS trip an
// unsupported addrspacecast static initializer, r11 compile failure)
#define SAH(b) (smem + (b) * 4096)
#define SAL(b) (smem + 8192 + (b) * 4096)
#define SWH(b) (smem + 16384 + (b) * 6144)
#define SWL(b) (smem + 28672 + (b) * 6144)

// ---------------- prep kernels (once per launch) ----------------
__global__ void conv3_kernel(const float* __restrict__ w1, const float* __restrict__ w2,
                             const float* __restrict__ w3,
                             _Float16* o1h, _Float16* o1l, _Float16* o2h, _Float16* o2l,
                             _Float16* o3h, _Float16* o3l) {
    int i = blockIdx.x * 256 + threadIdx.x;
    if (i < G3H * H) {
        const int r = i >> 9, k = i & 511;
        const size_t d = (size_t)r * H + swzk(r, k);
        split_f16(w1[i], &o1h[d], &o1l[d]);
        split_f16(w2[i], &o2h[d], &o2l[d]);
        split_f16(w3[i], &o3h[d], &o3l[d]);
    }
}

__global__ void prep_kernel(const float* __restrict__ h01, const float* __restrict__ h02,
                            _Float16* h1h, _Float16* h1l, _Float16* h2h, _Float16* h2l) {
    int i = blockIdx.x * 256 + threadIdx.x;
    if (i < B * H) {
        const int r = i >> 9, k = i & 511;
        const size_t d = (size_t)r * H + swzk(r, k);
        split_f16(h01[i], &h1h[d], &h1l[d]);
        split_f16(h02[i], &h2h[d], &h2l[d]);
    }
}

// ---------------- staging: one 64x64 A-tile + 3-gate 32-col W tile (A 16KB + W 24KB) ----------------
__device__ __forceinline__ void stage_tile32(
    const _Float16* __restrict__ Ahp, const _Float16* __restrict__ Alp,
    const _Float16* __restrict__ Whp, const _Float16* __restrict__ Wlp,
    int m0, int n0, int k0, int tid, int wv,
    _Float16* sAh, _Float16* sAl, _Float16* sWh, _Float16* sWl)
{
    {
        const int row = tid >> 3, kc = tid & 7;
        const size_t off = (size_t)(m0 + row) * H + k0 + kc * 8;
        stage16(Ahp + off, &sAh[(wv * 64) * 8]);
        stage16(Alp + off, &sAl[(wv * 64) * 8]);
    }
    {
        const int g = tid >> 8, rem = tid & 255;     // gates 0,1
        const int nr = rem >> 3, kc = rem & 7;
        const size_t off = (size_t)(g * H + n0 + nr) * H + k0 + kc * 8;
        stage16(Whp + off, &sWh[(wv * 64) * 8]);
        stage16(Wlp + off, &sWl[(wv * 64) * 8]);
    }
    if (tid < 256) {                                  // gate 2
        const int nr = tid >> 3, kc = tid & 7;
        const size_t off = (size_t)(2 * H + n0 + nr) * H + k0 + kc * 8;
        stage16(Whp + off, &sWh[(512 + wv * 64) * 8]);
        stage16(Wlp + off, &sWl[(512 + wv * 64) * 8]);
    }
}

// ---------------- K-half compute: wave = 32 rows x 16 cols x 3 gates x ONE K-half ----------------
// 10 ds_read_b128/wave/tile (4 A + 6 W) vs 16 before; kh-pair accs merged at epilogue.
// NS = acc sets; SN = set for gate 2 (gates 0,1 -> sets 0,1).
template <int SN, int NS>
__device__ __forceinline__ void compute_half(
    const _Float16* sAh_, const _Float16* sAl_,
    const _Float16* sWh_, const _Float16* sWl_,
    int wm, int wn, int kh, int ln, int qd,
    float4v (&accH)[NS][2], float4v (&accL)[NS][2])
{
    const int c = kh * 4 + qd;
    half8 afh[2], afl[2];
    #pragma unroll
    for (int ms = 0; ms < 2; ++ms) {
        const int row = wm * 32 + ms * 16 + ln;
        const int ai = row * 64 + ((c ^ (row & 7)) << 3);
        afh[ms] = *(const half8*)&sAh_[ai];
        afl[ms] = *(const half8*)&sAl_[ai];
    }
    const int nr = wn * 16 + ln;
    #pragma unroll
    for (int g = 0; g < 3; ++g) {
        const int s = (g < 2) ? g : SN;
        const int wi = (g * 32 + nr) * 64 + ((c ^ (nr & 7)) << 3);
        half8 bh = *(const half8*)&sWh_[wi];
        half8 bl = *(const half8*)&sWl_[wi];
        #pragma unroll
        for (int ms = 0; ms < 2; ++ms) {
            accH[s][ms] = __builtin_amdgcn_mfma_f32_16x16x32_f16(afh[ms], bh, accH[s][ms], 0, 0, 0);
            accL[s][ms] = __builtin_amdgcn_mfma_f32_16x16x32_f16(afh[ms], bl, accL[s][ms], 0, 0, 0);
            accL[s][ms] = __builtin_amdgcn_mfma_f32_16x16x32_f16(afl[ms], bh, accL[s][ms], 0, 0, 0);
        }
    }
}

// ---------------- layer-1 GRU step — N=32/80KB/2-block + K-half split ----------------
// waves: kh=wv&1 (K-half), wn=(wv>>1)&1 (16-col half), wm=wv>>2 (32-row half).
__global__ __launch_bounds__(512, 4) void gru1_kernel(
    const _Float16* __restrict__ Ah, const _Float16* __restrict__ Al,    // h1 prev swz
    const _Float16* __restrict__ Wh, const _Float16* __restrict__ Wl,    // wh1 swz
    const float* __restrict__ ypart,
    const float* __restrict__ bout,
    const float* __restrict__ y0, const float* __restrict__ cmd_t,
    const float* __restrict__ W_ih1,
    const float* __restrict__ b_ih1, const float* __restrict__ b_hh1,
    _Float16* __restrict__ hnh, _Float16* __restrict__ hnl,
    float* __restrict__ out, int t)
{
    __shared__ _Float16 smem[40960];   // 80 KB, carved via SAH/SAL/SWH/SWL macros

    const int tid = threadIdx.x;
    const int wv = tid >> 6, lane = tid & 63;
    const int kh = wv & 1, wn = (wv >> 1) & 1, wm = wv >> 2;
    const int ln = lane & 15, qd = lane >> 4;
    const int n0 = (blockIdx.x & 15) * 32;
    const int m0 = (blockIdx.x >> 4) * 64;

    stage_tile32(Ah, Al, Wh, Wl, m0, n0, 0, tid, wv, SAH(0), SAL(0), SWH(0), SWL(0));

    float4v accH[3][2], accL[3][2];
    #pragma unroll
    for (int s = 0; s < 3; ++s)
        #pragma unroll
        for (int ms = 0; ms < 2; ++ms) { accH[s][ms] = (float4v)(0.f); accL[s][ms] = (float4v)(0.f); }

    // ---- K-loop: gh = h1_prev @ W_hh1^T (8 tiles, dbuf); each wave does its K-half ----
    for (int it = 0; it < 8; ++it) {
        const int buf = it & 1;
        __syncthreads();
        if (it + 1 < 8)
            stage_tile32(Ah, Al, Wh, Wl, m0, n0, (it + 1) * 64, tid, wv,
                         SAH(buf ^ 1), SAL(buf ^ 1), SWH(buf ^ 1), SWL(buf ^ 1));
        compute_half<2, 3>(SAH(buf), SAL(buf), SWH(buf), SWL(buf), wm, wn, kh, ln, qd, accH, accL);
    }

    __syncthreads();   // all tile reads done before overlays

    // kh=1 waves park their half-K accs in LDS scratch (48KB at SWH region),
    // layout [j][pair][lane] -> conflict-free b128.
    float4v* mg = (float4v*)(smem + 16384);
    const int pr = wm * 2 + wn;
    if (kh == 1) {
        #pragma unroll
        for (int s = 0; s < 3; ++s)
            #pragma unroll
            for (int ms = 0; ms < 2; ++ms) {
                mg[(s * 2 + ms) * 256 + pr * 64 + lane] = accH[s][ms];
                mg[(6 + s * 2 + ms) * 256 + pr * 64 + lane] = accL[s][ms];
            }
    }

    // sX = [y_{t-1}, cmd_t] on SAH(0) overlay (disjoint from merge region)
    float* sX = (float*)&smem[0];
    const int yr = tid >> 3, yp = tid & 7;
    if (t == 0) {
        if (tid < 64) {
            #pragma unroll
            for (int o2 = 0; o2 < NO; ++o2)
                sX[tid * 8 + o2] = y0[(size_t)(m0 + tid) * NO + o2];
        }
    } else {
        const int row = m0 + yr;
        float a5[NO];
        #pragma unroll
        for (int o2 = 0; o2 < NO; ++o2) {
            const float4 v = *(const float4*)(ypart + ((size_t)row * NO + o2) * 32 + yp * 4);
            a5[o2] = (v.x + v.y) + (v.z + v.w);
        }
        #pragma unroll
        for (int off = 1; off < 8; off <<= 1)
            #pragma unroll
            for (int o2 = 0; o2 < NO; ++o2) a5[o2] += __shfl_xor(a5[o2], off, 64);
        if (yp == 0) {
            #pragma unroll
            for (int o2 = 0; o2 < NO; ++o2) {
                const float y = a5[o2] + bout[o2];
                sX[yr * 8 + o2] = y;
                if (n0 == 0)
                    out[(size_t)(m0 + yr) * (T * NO) + (size_t)(t - 1) * NO + o2] = y;
            }
        }
    }
    if (tid < 64) {
        #pragma unroll
        for (int c = 0; c < NC; ++c)
            sX[tid * 8 + NO + c] = cmd_t[(size_t)(m0 + tid) * NC + c];
    }
    __syncthreads();

    if (kh != 0) return;   // kh=0 waves merge + run the epilogue

    #pragma unroll
    for (int s = 0; s < 3; ++s)
        #pragma unroll
        for (int ms = 0; ms < 2; ++ms) {
            accH[s][ms] += mg[(s * 2 + ms) * 256 + pr * 64 + lane];
            accL[s][ms] += mg[(6 + s * 2 + ms) * 256 + pr * 64 + lane];
        }

    // ---- epilogue: fp32 input path (K=8, W_ih1/biases direct from L2) + gates + blend ----
    const int gnl = wn * 16 + ln;
    const int gn = n0 + gnl;
    float wi[3][8];
    #pragma unroll
    for (int g = 0; g < 3; ++g) {
        const float4 w0 = *(const float4*)(W_ih1 + (size_t)(g * H + gn) * 8);
        const float4 w1 = *(const float4*)(W_ih1 + (size_t)(g * H + gn) * 8 + 4);
        wi[g][0] = w0.x; wi[g][1] = w0.y; wi[g][2] = w0.z; wi[g][3] = w0.w;
        wi[g][4] = w1.x; wi[g][5] = w1.y; wi[g][6] = w1.z; wi[g][7] = w1.w;
    }
    const float bi0 = b_ih1[0 * H + gn], bi1 = b_ih1[1 * H + gn], bi2 = b_ih1[2 * H + gn];
    const float bh0 = b_hh1[0 * H + gn], bh1 = b_hh1[1 * H + gn], bh2 = b_hh1[2 * H + gn];
    #pragma unroll
    for (int ms = 0; ms < 2; ++ms) {
        #pragma unroll
        for (int r = 0; r < 4; ++r) {
            const int mloc = wm * 32 + ms * 16 + qd * 4 + r;
            const int m = m0 + mloc;
            float giR = bi0, giZ = bi1, giN = bi2;
            #pragma unroll
            for (int k = 0; k < 8; ++k) {
                const float xv = sX[mloc * 8 + k];
                giR = fmaf(xv, wi[0][k], giR);
                giZ = fmaf(xv, wi[1][k], giZ);
                giN = fmaf(xv, wi[2][k], giN);
            }
            const float gR = giR + bh0 + accH[0][ms][r] + accL[0][ms][r] * INV_LO;
            const float gZ = giZ + bh1 + accH[1][ms][r] + accL[1][ms][r] * INV_LO;
            const float gNh = bh2 + accH[2][ms][r] + accL[2][ms][r] * INV_LO;
            const float R = sigmoidf_(gR), Z = sigmoidf_(gZ);
            const float N = tanhf(fmaf(R, gNh, giN));
            const size_t idx = hidx(m, gn);
            const float hp = (float)Ah[idx] + (float)Al[idx] * INV_LO;
            const float hv = (1.f - Z) * N + Z * hp;
            split_f16(hv, &hnh[idx], &hnl[idx]);
        }
    }
}

// ---------------- layer-2 GRU step — N=32/80KB/2-block + K-half split + y-partials ----------------
__global__ __launch_bounds__(512, 4) void gru2_kernel(
    const _Float16* __restrict__ Aih, const _Float16* __restrict__ Ail,  // h1 cur swz
    const _Float16* __restrict__ Wih, const _Float16* __restrict__ Wil,  // wi2 swz
    const _Float16* __restrict__ Ahh, const _Float16* __restrict__ Ahl,  // h2 prev swz
    const _Float16* __restrict__ Whh, const _Float16* __restrict__ Whl,  // wh2 swz
    const float* __restrict__ b_i, const float* __restrict__ b_h,
    const float* __restrict__ Wout,
    _Float16* __restrict__ hnh, _Float16* __restrict__ hnl,
    float* __restrict__ ypart)
{
    __shared__ _Float16 smem[40960];   // 80 KB

    const int tid = threadIdx.x;
    const int wv = tid >> 6, lane = tid & 63;
    const int kh = wv & 1, wn = (wv >> 1) & 1, wm = wv >> 2;
    const int ln = lane & 15, qd = lane >> 4;
    const int n0 = (blockIdx.x & 15) * 32;
    const int m0 = (blockIdx.x >> 4) * 64;

    float4v accH[4][2], accL[4][2];
    #pragma unroll
    for (int s = 0; s < 4; ++s)
        #pragma unroll
        for (int ms = 0; ms < 2; ++ms) { accH[s][ms] = (float4v)(0.f); accL[s][ms] = (float4v)(0.f); }

    stage_tile32(Aih, Ail, Wih, Wil, m0, n0, 0, tid, wv, SAH(0), SAL(0), SWH(0), SWL(0));
    for (int it = 0; it < 16; ++it) {
        const int buf = it & 1;
        __syncthreads();
        if (it + 1 < 16) {
            const int k0 = ((it + 1) & 7) * 64;
            if (it + 1 < 8)
                stage_tile32(Aih, Ail, Wih, Wil, m0, n0, k0, tid, wv,
                             SAH(buf ^ 1), SAL(buf ^ 1), SWH(buf ^ 1), SWL(buf ^ 1));
            else
                stage_tile32(Ahh, Ahl, Whh, Whl, m0, n0, k0, tid, wv,
                             SAH(buf ^ 1), SAL(buf ^ 1), SWH(buf ^ 1), SWL(buf ^ 1));
        }
        if (it < 8)
            compute_half<2, 4>(SAH(buf), SAL(buf), SWH(buf), SWL(buf), wm, wn, kh, ln, qd, accH, accL);
        else
            compute_half<3, 4>(SAH(buf), SAL(buf), SWH(buf), SWL(buf), wm, wn, kh, ln, qd, accH, accL);
    }

    __syncthreads();   // all tile reads done before scratch overlay

    // kh=1 waves park accs (64KB scratch at smem base, [j][pair][lane] conflict-free)
    float4v* mg = (float4v*)smem;
    const int pr = wm * 2 + wn;
    if (kh == 1) {
        #pragma unroll
        for (int s = 0; s < 4; ++s)
            #pragma unroll
            for (int ms = 0; ms < 2; ++ms) {
                mg[(s * 2 + ms) * 256 + pr * 64 + lane] = accH[s][ms];
                mg[(8 + s * 2 + ms) * 256 + pr * 64 + lane] = accL[s][ms];
            }
    }
    __syncthreads();
    if (kh != 0) return;

    #pragma unroll
    for (int s = 0; s < 4; ++s)
        #pragma unroll
        for (int ms = 0; ms < 2; ++ms) {
            accH[s][ms] += mg[(s * 2 + ms) * 256 + pr * 64 + lane];
            accL[s][ms] += mg[(8 + s * 2 + ms) * 256 + pr * 64 + lane];
        }

    // epilogue: biases direct from global; emit per-16-col y partials (no atomics)
    const int gnl = wn * 16 + ln;
    const int gn = n0 + gnl;
    const float bi0 = b_i[0 * H + gn], bi1 = b_i[1 * H + gn], bi2 = b_i[2 * H + gn];
    const float bh0 = b_h[0 * H + gn], bh1 = b_h[1 * H + gn], bh2 = b_h[2 * H + gn];
    const float wo0 = Wout[0 * H + gn], wo1 = Wout[1 * H + gn], wo2 = Wout[2 * H + gn];
    const float wo3 = Wout[3 * H + gn], wo4 = Wout[4 * H + gn];
    const int ws = (blockIdx.x & 15) * 2 + wn;        // 32 column slices of 16
    #pragma unroll
    for (int ms = 0; ms < 2; ++ms) {
        #pragma unroll
        for (int r = 0; r < 4; ++r) {
            const int m = m0 + wm * 32 + ms * 16 + qd * 4 + r;
            const float gR = bi0 + bh0 + accH[0][ms][r] + accL[0][ms][r] * INV_LO;
            const float gZ = bi1 + bh1 + accH[1][ms][r] + accL[1][ms][r] * INV_LO;
            const float gNi = bi2 + accH[2][ms][r] + accL[2][ms][r] * INV_LO;
            const float gNh = bh2 + accH[3][ms][r] + accL[3][ms][r] * INV_LO;
            const float R = sigmoidf_(gR), Z = sigmoidf_(gZ);
            const float N = tanhf(fmaf(R, gNh, gNi));
            const size_t idx = hidx(m, gn);
            const float hp = (float)Ahh[idx] + (float)Ahl[idx] * INV_LO;
            const float hv = (1.f - Z) * N + Z * hp;
            split_f16(hv, &hnh[idx], &hnl[idx]);

            float p0 = hv * wo0, p1 = hv * wo1, p2 = hv * wo2, p3 = hv * wo3, p4 = hv * wo4;
            #pragma unroll
            for (int off = 1; off < 16; off <<= 1) {
                p0 += __shfl_xor(p0, off, 64);
                p1 += __shfl_xor(p1, off, 64);
                p2 += __shfl_xor(p2, off, 64);
                p3 += __shfl_xor(p3, off, 64);
                p4 += __shfl_xor(p4, off, 64);
            }
            if (ln == 0) {
                float* yp = ypart + (size_t)m * NO * 32 + ws;
                yp[0 * 32] = p0;
                yp[1 * 32] = p1;
                yp[2 * 32] = p2;
                yp[3 * 32] = p3;
                yp[4 * 32] = p4;
            }
        }
    }
}

// ---------------- final-step output projection ----------------
__global__ __launch_bounds__(256) void yout_final_kernel(
    const _Float16* __restrict__ h2h, const _Float16* __restrict__ h2l,
    const float* __restrict__ Wout, const float* __restrict__ bout,
    float* __restrict__ out)
{
    const int wv = threadIdx.x >> 6, lane = threadIdx.x & 63;
    const int b = blockIdx.x * 4 + wv;
    const size_t hb = (size_t)b * H + lane * 8;
    half8 hh = *(const half8*)(h2h + hb);
    half8 hl = *(const half8*)(h2l + hb);
    const int tl = lane >> 3, cw = lane & 7;
    const int kbase = tl * 64 + ((cw ^ (b & 7)) << 3);
    float hv[8];
    #pragma unroll
    for (int j = 0; j < 8; ++j) hv[j] = (float)hh[j] + (float)hl[j] * INV_LO;
    float acc[NO];
    #pragma unroll
    for (int o = 0; o < NO; ++o) {
        acc[o] = 0.f;
        const float* w = Wout + (size_t)o * H + kbase;
        #pragma unroll
        for (int j = 0; j < 8; ++j) acc[o] = fmaf(hv[j], w[j], acc[o]);
    }
    #pragma unroll
    for (int off = 32; off > 0; off >>= 1)
        #pragma unroll
        for (int o = 0; o < NO; ++o) acc[o] += __shfl_down(acc[o], off, 64);
    if (lane == 0) {
        #pragma unroll
        for (int o = 0; o < NO; ++o)
            out[(size_t)b * (T * NO) + (size_t)(T - 1) * NO + o] = acc[o] + bout[o];
    }
}

extern "C" void kernel_launch(void* const* d_in, const int* in_sizes, int n_in,
                              void* d_out, int out_size, void* d_ws, size_t ws_size,
                              hipStream_t stream) {
    (void)in_sizes; (void)n_in; (void)out_size; (void)ws_size;
    const float* cmds  = (const float*)d_in[1];
    const float* y0    = (const float*)d_in[2];
    const float* h01   = (const float*)d_in[3];
    const float* h02   = (const float*)d_in[4];
    const float* W_ih1 = (const float*)d_in[5];
    const float* W_hh1 = (const float*)d_in[6];
    const float* b_ih1 = (const float*)d_in[7];
    const float* b_hh1 = (const float*)d_in[8];
    const float* W_ih2 = (const float*)d_in[9];
    const float* W_hh2 = (const float*)d_in[10];
    const float* b_ih2 = (const float*)d_in[11];
    const float* b_hh2 = (const float*)d_in[12];
    const float* W_out = (const float*)d_in[13];
    const float* b_out = (const float*)d_in[14];
    float* out = (float*)d_out;

    // ---- workspace (~27 MB) ----
    char* ws = (char*)d_ws;
    size_t o = 0;
    const size_t WSZ = (size_t)G3H * H * sizeof(_Float16);
    _Float16* wh1h = (_Float16*)(ws + o); o += WSZ;
    _Float16* wh1l = (_Float16*)(ws + o); o += WSZ;
    _Float16* wi2h = (_Float16*)(ws + o); o += WSZ;
    _Float16* wi2l = (_Float16*)(ws + o); o += WSZ;
    _Float16* wh2h = (_Float16*)(ws + o); o += WSZ;
    _Float16* wh2l = (_Float16*)(ws + o); o += WSZ;
    _Float16 *h1h[2], *h1l[2], *h2h[2], *h2l[2];
    for (int i = 0; i < 2; ++i) { h1h[i] = (_Float16*)(ws + o); o += BHE * 2; }
    for (int i = 0; i < 2; ++i) { h1l[i] = (_Float16*)(ws + o); o += BHE * 2; }
    for (int i = 0; i < 2; ++i) { h2h[i] = (_Float16*)(ws + o); o += BHE * 2; }
    for (int i = 0; i < 2; ++i) { h2l[i] = (_Float16*)(ws + o); o += BHE * 2; }
    float* ypart = (float*)(ws + o); o += (size_t)B * NO * 32 * sizeof(float);

    conv3_kernel<<<(G3H * H + 255) / 256, 256, 0, stream>>>(
        W_hh1, W_ih2, W_hh2, wh1h, wh1l, wi2h, wi2l, wh2h, wh2l);
    prep_kernel<<<(B * H + 255) / 256, 256, 0, stream>>>(
        h01, h02, h1h[0], h1l[0], h2h[0], h2l[0]);

    for (int t = 0; t < T; ++t) {
        const int si = t & 1, so = si ^ 1;

        gru1_kernel<<<512, 512, 0, stream>>>(
            h1h[si], h1l[si], wh1h, wh1l,
            ypart, b_out,
            y0, cmds + (size_t)t * B * NC,
            W_ih1, b_ih1, b_hh1,
            h1h[so], h1l[so],
            out, t);

        gru2_kernel<<<512, 512, 0, stream>>>(
            h1h[so], h1l[so], wi2h, wi2l,
            h2h[si], h2l[si], wh2h, wh2l,
            b_ih2, b_hh2, W_out,
            h2h[so], h2l[so],
            ypart);
    }

    // final y_{T-1}: T even -> final h2 in slot 0
    yout_final_kernel<<<B / 4, 256, 0, stream>>>(
        h2h[0], h2l[0], W_out, b_out, out);
}

// Round 13
// 6064.228 us; speedup vs baseline: 1.0732x; 1.0732x over previous
//
#include <hip/hip_runtime.h>
#include <math.h>

// Problem constants
#define B 2048
#define T 128
#define H 512
#define NC 3
#define NO 5
#define G3H 1536
#define BHE ((size_t)B * H)

typedef _Float16 half8 __attribute__((ext_vector_type(8)));
typedef float float4v __attribute__((ext_vector_type(4)));

#define LO_SCALE 1024.0f
#define INV_LO (1.0f / 1024.0f)
#define F16_MIN_NORM 6.103515625e-05f

__device__ __forceinline__ float sigmoidf_(float x) { return 1.0f / (1.0f + __expf(-x)); }

// Split fp32 -> (hi, lo*1024) f16 pair; hi zeroed in subnormal range (flush safety).
__device__ __forceinline__ void split_f16(float a, _Float16* hi, _Float16* lo) {
    _Float16 h = (_Float16)a;
    if (fabsf(a) < F16_MIN_NORM) h = (_Float16)0.0f;
    *hi = h;
    *lo = (_Float16)((a - (float)h) * LO_SCALE);
}

// element (row,k) of a 512-col matrix stored at row*512 + swzk(row,k):
// 16B chunk c=(k>>3)&7 lives in slot c ^ (row&7)  (LDS-conflict-free fragments)
__device__ __forceinline__ int swzk(int row, int k) {
    return (k & ~63) | ((((k >> 3) & 7) ^ (row & 7)) << 3) | (k & 7);
}
__device__ __forceinline__ size_t hidx(int row, int k) {
    return (size_t)row * H + swzk(row, k);
}

// async 16B global->LDS (wave-uniform LDS base; lane lands at base + lane*16B)
__device__ __forceinline__ void stage16(const _Float16* gp, _Float16* lp) {
    __builtin_amdgcn_global_load_lds(
        (const __attribute__((address_space(1))) unsigned int*)gp,
        (__attribute__((address_space(3))) unsigned int*)lp,
        16, 0, 0);
}

// ---------------- prep kernels (once per launch) ----------------
__global__ void conv3_kernel(const float* __restrict__ w1, const float* __restrict__ w2,
                             const float* __restrict__ w3,
                             _Float16* o1h, _Float16* o1l, _Float16* o2h, _Float16* o2l,
                             _Float16* o3h, _Float16* o3l) {
    int i = blockIdx.x * 256 + threadIdx.x;
    if (i < G3H * H) {
        const int r = i >> 9, k = i & 511;
        const size_t d = (size_t)r * H + swzk(r, k);
        split_f16(w1[i], &o1h[d], &o1l[d]);
        split_f16(w2[i], &o2h[d], &o2l[d]);
        split_f16(w3[i], &o3h[d], &o3l[d]);
    }
}

__global__ void prep_kernel(const float* __restrict__ h01, const float* __restrict__ h02,
                            _Float16* h1h, _Float16* h1l, _Float16* h2h, _Float16* h2l) {
    int i = blockIdx.x * 256 + threadIdx.x;
    if (i < B * H) {
        const int r = i >> 9, k = i & 511;
        const size_t d = (size_t)r * H + swzk(r, k);
        split_f16(h01[i], &h1h[d], &h1l[d]);
        split_f16(h02[i], &h2h[d], &h2l[d]);
    }
}

// ---------------- staging: 3-gate 32-col W tile only (24KB; A bypasses LDS) ----------------
// 768 chunks per comp: threads 0-511 -> gates 0,1; threads 0-255 -> gate 2.
__device__ __forceinline__ void stage_w32(
    const _Float16* __restrict__ Whp, const _Float16* __restrict__ Wlp,
    int n0, int k0, int tid, int wv,
    _Float16* sWh, _Float16* sWl)
{
    {
        const int g = tid >> 8, rem = tid & 255;     // gates 0,1
        const int nr = rem >> 3, kc = rem & 7;
        const size_t off = (size_t)(g * H + n0 + nr) * H + k0 + kc * 8;
        stage16(Whp + off, &sWh[(wv * 64) * 8]);
        stage16(Wlp + off, &sWl[(wv * 64) * 8]);
    }
    if (tid < 256) {                                  // gate 2
        const int nr = tid >> 3, kc = tid & 7;
        const size_t off = (size_t)(2 * H + n0 + nr) * H + k0 + kc * 8;
        stage16(Whp + off, &sWh[(512 + wv * 64) * 8]);
        stage16(Wlp + off, &sWl[(512 + wv * 64) * 8]);
    }
}

// ---------------- A fragments direct from global (L2-resident, swizzled layout) ----------------
// Per lane: 4x aligned 16B loads (ks=0,1 x hi/lo). row&7 == ln&7 (m0,wm*16 are mult of 8/16).
__device__ __forceinline__ void loadA(
    const _Float16* __restrict__ Ahp, const _Float16* __restrict__ Alp,
    int m0, int k0, int wm, int ln, int qd,
    half8 (&ah)[2], half8 (&al)[2])
{
    const int row = wm * 16 + ln;
    const size_t rb = (size_t)(m0 + row) * H + k0;
    const int c0 = ((qd) ^ (ln & 7)) << 3;
    const int c1 = ((4 + qd) ^ (ln & 7)) << 3;
    ah[0] = *(const half8*)(Ahp + rb + c0);
    al[0] = *(const half8*)(Alp + rb + c0);
    ah[1] = *(const half8*)(Ahp + rb + c1);
    al[1] = *(const half8*)(Alp + rb + c1);
}

// ---------------- N=32 compute: A from regs, W from LDS (wave: 16 rows x 16 cols x 3 gates) ----
// NS = acc array size; SN = set index for gate 2 (gates 0,1 -> sets 0,1).
template <int SN, int NS>
__device__ __forceinline__ void compute_w(
    const half8 (&ah)[2], const half8 (&al)[2],
    const _Float16* sWh_, const _Float16* sWl_,
    int wn, int ln, int qd,
    float4v (&accH)[NS], float4v (&accL)[NS])
{
    #pragma unroll
    for (int ks = 0; ks < 2; ++ks) {
        const int c = ks * 4 + qd;
        const int nr = wn * 16 + ln;
        #pragma unroll
        for (int g = 0; g < 3; ++g) {
            const int s = (g < 2) ? g : SN;
            const int wi = (g * 32 + nr) * 64 + ((c ^ (nr & 7)) << 3);
            half8 bh = *(const half8*)&sWh_[wi];
            half8 bl = *(const half8*)&sWl_[wi];
            accH[s] = __builtin_amdgcn_mfma_f32_16x16x32_f16(ah[ks], bh, accH[s], 0, 0, 0);
            accL[s] = __builtin_amdgcn_mfma_f32_16x16x32_f16(ah[ks], bl, accL[s], 0, 0, 0);
            accL[s] = __builtin_amdgcn_mfma_f32_16x16x32_f16(al[ks], bh, accL[s], 0, 0, 0);
        }
    }
}

// ---------------- layer-1 GRU step — N=32, W-only LDS (50KB) -> 2 blocks/CU ----------------
__global__ __launch_bounds__(512, 4) void gru1_kernel(
    const _Float16* __restrict__ Ah, const _Float16* __restrict__ Al,    // h1 prev swz
    const _Float16* __restrict__ Wh, const _Float16* __restrict__ Wl,    // wh1 swz
    const float* __restrict__ ypart,
    const float* __restrict__ bout,
    const float* __restrict__ y0, const float* __restrict__ cmd_t,
    const float* __restrict__ W_ih1,
    const float* __restrict__ b_ih1, const float* __restrict__ b_hh1,
    _Float16* __restrict__ hnh, _Float16* __restrict__ hnl,
    float* __restrict__ out, int t)
{
    __shared__ _Float16 sWh[2][6144], sWl[2][6144];   // 48 KB
    __shared__ float sX[64 * 8];                       // +2 KB

    const int tid = threadIdx.x;
    const int wv = tid >> 6, lane = tid & 63;
    const int wm = wv >> 1, wn = wv & 1;
    const int ln = lane & 15, qd = lane >> 4;
    const int n0 = (blockIdx.x & 15) * 32;
    const int m0 = (blockIdx.x >> 4) * 64;

    stage_w32(Wh, Wl, n0, 0, tid, wv, sWh[0], sWl[0]);

    half8 cah[2], cal[2], nah[2], nal[2];
    loadA(Ah, Al, m0, 0, wm, ln, qd, cah, cal);

    float4v accH[3], accL[3];
    #pragma unroll
    for (int s = 0; s < 3; ++s) { accH[s] = (float4v)(0.f); accL[s] = (float4v)(0.f); }

    // ---- K-loop: gh = h1_prev @ W_hh1^T (8 tiles; W dbuf in LDS, A reg-prefetched) ----
    for (int it = 0; it < 8; ++it) {
        const int buf = it & 1;
        __syncthreads();
        if (it + 1 < 8) {
            stage_w32(Wh, Wl, n0, (it + 1) * 64, tid, wv, sWh[buf ^ 1], sWl[buf ^ 1]);
            loadA(Ah, Al, m0, (it + 1) * 64, wm, ln, qd, nah, nal);
        }
        compute_w<2, 3>(cah, cal, sWh[buf], sWl[buf], wn, ln, qd, accH, accL);
        cah[0] = nah[0]; cah[1] = nah[1];
        cal[0] = nal[0]; cal[1] = nal[1];
    }

    // ---- sX = [y_{t-1}, cmd_t] ----
    const int yr = tid >> 3, yp = tid & 7;   // row, slice-quad
    if (t == 0) {
        if (tid < 64) {
            #pragma unroll
            for (int o2 = 0; o2 < NO; ++o2)
                sX[tid * 8 + o2] = y0[(size_t)(m0 + tid) * NO + o2];
        }
    } else {
        const int row = m0 + yr;
        float a5[NO];
        #pragma unroll
        for (int o2 = 0; o2 < NO; ++o2) {
            const float4 v = *(const float4*)(ypart + ((size_t)row * NO + o2) * 32 + yp * 4);
            a5[o2] = (v.x + v.y) + (v.z + v.w);
        }
        #pragma unroll
        for (int off = 1; off < 8; off <<= 1)
            #pragma unroll
            for (int o2 = 0; o2 < NO; ++o2) a5[o2] += __shfl_xor(a5[o2], off, 64);
        if (yp == 0) {
            #pragma unroll
            for (int o2 = 0; o2 < NO; ++o2) {
                const float y = a5[o2] + bout[o2];
                sX[yr * 8 + o2] = y;
                if (n0 == 0)
                    out[(size_t)(m0 + yr) * (T * NO) + (size_t)(t - 1) * NO + o2] = y;
            }
        }
    }
    if (tid < 64) {
        #pragma unroll
        for (int c = 0; c < NC; ++c)
            sX[tid * 8 + NO + c] = cmd_t[(size_t)(m0 + tid) * NC + c];
    }
    __syncthreads();

    // ---- epilogue: fp32 input path (K=8, W_ih1/biases direct from L2) + gates + blend ----
    const int gnl = wn * 16 + ln;
    const int gn = n0 + gnl;
    float wi[3][8];
    #pragma unroll
    for (int g = 0; g < 3; ++g) {
        const float4 w0 = *(const float4*)(W_ih1 + (size_t)(g * H + gn) * 8);
        const float4 w1 = *(const float4*)(W_ih1 + (size_t)(g * H + gn) * 8 + 4);
        wi[g][0] = w0.x; wi[g][1] = w0.y; wi[g][2] = w0.z; wi[g][3] = w0.w;
        wi[g][4] = w1.x; wi[g][5] = w1.y; wi[g][6] = w1.z; wi[g][7] = w1.w;
    }
    const float bi0 = b_ih1[0 * H + gn], bi1 = b_ih1[1 * H + gn], bi2 = b_ih1[2 * H + gn];
    const float bh0 = b_hh1[0 * H + gn], bh1 = b_hh1[1 * H + gn], bh2 = b_hh1[2 * H + gn];
    #pragma unroll
    for (int r = 0; r < 4; ++r) {
        const int mloc = wm * 16 + qd * 4 + r;
        const int m = m0 + mloc;
        float giR = bi0, giZ = bi1, giN = bi2;
        #pragma unroll
        for (int k = 0; k < 8; ++k) {
            const float xv = sX[mloc * 8 + k];
            giR = fmaf(xv, wi[0][k], giR);
            giZ = fmaf(xv, wi[1][k], giZ);
            giN = fmaf(xv, wi[2][k], giN);
        }
        const float gR = giR + bh0 + accH[0][r] + accL[0][r] * INV_LO;
        const float gZ = giZ + bh1 + accH[1][r] + accL[1][r] * INV_LO;
        const float gNh = bh2 + accH[2][r] + accL[2][r] * INV_LO;
        const float R = sigmoidf_(gR), Z = sigmoidf_(gZ);
        const float N = tanhf(fmaf(R, gNh, giN));
        const size_t idx = hidx(m, gn);
        const float hp = (float)Ah[idx] + (float)Al[idx] * INV_LO;
        const float hv = (1.f - Z) * N + Z * hp;
        split_f16(hv, &hnh[idx], &hnl[idx]);
    }
}

// ---------------- layer-2 GRU step — N=32, W-only LDS (48KB) -> 2 blocks/CU + y-partials ----------------
__global__ __launch_bounds__(512, 4) void gru2_kernel(
    const _Float16* __restrict__ Aih, const _Float16* __restrict__ Ail,  // h1 cur swz
    const _Float16* __restrict__ Wih, const _Float16* __restrict__ Wil,  // wi2 swz
    const _Float16* __restrict__ Ahh, const _Float16* __restrict__ Ahl,  // h2 prev swz
    const _Float16* __restrict__ Whh, const _Float16* __restrict__ Whl,  // wh2 swz
    const float* __restrict__ b_i, const float* __restrict__ b_h,
    const float* __restrict__ Wout,
    _Float16* __restrict__ hnh, _Float16* __restrict__ hnl,
    float* __restrict__ ypart)
{
    __shared__ _Float16 sWh[2][6144], sWl[2][6144];   // 48 KB

    const int tid = threadIdx.x;
    const int wv = tid >> 6, lane = tid & 63;
    const int wm = wv >> 1, wn = wv & 1;
    const int ln = lane & 15, qd = lane >> 4;
    const int n0 = (blockIdx.x & 15) * 32;
    const int m0 = (blockIdx.x >> 4) * 64;

    float4v accH[4], accL[4];
    #pragma unroll
    for (int s = 0; s < 4; ++s) { accH[s] = (float4v)(0.f); accL[s] = (float4v)(0.f); }

    stage_w32(Wih, Wil, n0, 0, tid, wv, sWh[0], sWl[0]);

    half8 cah[2], cal[2], nah[2], nal[2];
    loadA(Aih, Ail, m0, 0, wm, ln, qd, cah, cal);

    // ---- K-loop: tiles 0-7 gi2 (A=h1 cur), tiles 8-15 gh2 (A=h2 prev) ----
    for (int it = 0; it < 16; ++it) {
        const int buf = it & 1;
        __syncthreads();
        if (it + 1 < 16) {
            const int k0 = ((it + 1) & 7) * 64;
            if (it + 1 < 8) {
                stage_w32(Wih, Wil, n0, k0, tid, wv, sWh[buf ^ 1], sWl[buf ^ 1]);
                loadA(Aih, Ail, m0, k0, wm, ln, qd, nah, nal);
            } else {
                stage_w32(Whh, Whl, n0, k0, tid, wv, sWh[buf ^ 1], sWl[buf ^ 1]);
                loadA(Ahh, Ahl, m0, k0, wm, ln, qd, nah, nal);
            }
        }
        if (it < 8)
            compute_w<2, 4>(cah, cal, sWh[buf], sWl[buf], wn, ln, qd, accH, accL);
        else
            compute_w<3, 4>(cah, cal, sWh[buf], sWl[buf], wn, ln, qd, accH, accL);
        cah[0] = nah[0]; cah[1] = nah[1];
        cal[0] = nal[0]; cal[1] = nal[1];
    }

    // epilogue: biases direct from global; emit per-16-col y partials (no atomics)
    const int gnl = wn * 16 + ln;
    const int gn = n0 + gnl;
    const float bi0 = b_i[0 * H + gn], bi1 = b_i[1 * H + gn], bi2 = b_i[2 * H + gn];
    const float bh0 = b_h[0 * H + gn], bh1 = b_h[1 * H + gn], bh2 = b_h[2 * H + gn];
    const float wo0 = Wout[0 * H + gn], wo1 = Wout[1 * H + gn], wo2 = Wout[2 * H + gn];
    const float wo3 = Wout[3 * H + gn], wo4 = Wout[4 * H + gn];
    const int ws = (blockIdx.x & 15) * 2 + wn;        // 32 column slices of 16
    #pragma unroll
    for (int r = 0; r < 4; ++r) {
        const int m = m0 + wm * 16 + qd * 4 + r;
        const float gR = bi0 + bh0 + accH[0][r] + accL[0][r] * INV_LO;
        const float gZ = bi1 + bh1 + accH[1][r] + accL[1][r] * INV_LO;
        const float gNi = bi2 + accH[2][r] + accL[2][r] * INV_LO;
        const float gNh = bh2 + accH[3][r] + accL[3][r] * INV_LO;
        const float R = sigmoidf_(gR), Z = sigmoidf_(gZ);
        const float N = tanhf(fmaf(R, gNh, gNi));
        const size_t idx = hidx(m, gn);
        const float hp = (float)Ahh[idx] + (float)Ahl[idx] * INV_LO;
        const float hv = (1.f - Z) * N + Z * hp;
        split_f16(hv, &hnh[idx], &hnl[idx]);

        float p0 = hv * wo0, p1 = hv * wo1, p2 = hv * wo2, p3 = hv * wo3, p4 = hv * wo4;
        #pragma unroll
        for (int off = 1; off < 16; off <<= 1) {
            p0 += __shfl_xor(p0, off, 64);
            p1 += __shfl_xor(p1, off, 64);
            p2 += __shfl_xor(p2, off, 64);
            p3 += __shfl_xor(p3, off, 64);
            p4 += __shfl_xor(p4, off, 64);
        }
        if (ln == 0) {
            float* yp = ypart + (size_t)m * NO * 32 + ws;
            yp[0 * 32] = p0;
            yp[1 * 32] = p1;
            yp[2 * 32] = p2;
            yp[3 * 32] = p3;
            yp[4 * 32] = p4;
        }
    }
}

// ---------------- final-step output projection ----------------
__global__ __launch_bounds__(256) void yout_final_kernel(
    const _Float16* __restrict__ h2h, const _Float16* __restrict__ h2l,
    const float* __restrict__ Wout, const float* __restrict__ bout,
    float* __restrict__ out)
{
    const int wv = threadIdx.x >> 6, lane = threadIdx.x & 63;
    const int b = blockIdx.x * 4 + wv;
    const size_t hb = (size_t)b * H + lane * 8;
    half8 hh = *(const half8*)(h2h + hb);
    half8 hl = *(const half8*)(h2l + hb);
    const int tl = lane >> 3, cw = lane & 7;
    const int kbase = tl * 64 + ((cw ^ (b & 7)) << 3);
    float hv[8];
    #pragma unroll
    for (int j = 0; j < 8; ++j) hv[j] = (float)hh[j] + (float)hl[j] * INV_LO;
    float acc[NO];
    #pragma unroll
    for (int o = 0; o < NO; ++o) {
        acc[o] = 0.f;
        const float* w = Wout + (size_t)o * H + kbase;
        #pragma unroll
        for (int j = 0; j < 8; ++j) acc[o] = fmaf(hv[j], w[j], acc[o]);
    }
    #pragma unroll
    for (int off = 32; off > 0; off >>= 1)
        #pragma unroll
        for (int o = 0; o < NO; ++o) acc[o] += __shfl_down(acc[o], off, 64);
    if (lane == 0) {
        #pragma unroll
        for (int o = 0; o < NO; ++o)
            out[(size_t)b * (T * NO) + (size_t)(T - 1) * NO + o] = acc[o] + bout[o];
    }
}

extern "C" void kernel_launch(void* const* d_in, const int* in_sizes, int n_in,
                              void* d_out, int out_size, void* d_ws, size_t ws_size,
                              hipStream_t stream) {
    (void)in_sizes; (void)n_in; (void)out_size; (void)ws_size;
    const float* cmds  = (const float*)d_in[1];
    const float* y0    = (const float*)d_in[2];
    const float* h01   = (const float*)d_in[3];
    const float* h02   = (const float*)d_in[4];
    const float* W_ih1 = (const float*)d_in[5];
    const float* W_hh1 = (const float*)d_in[6];
    const float* b_ih1 = (const float*)d_in[7];
    const float* b_hh1 = (const float*)d_in[8];
    const float* W_ih2 = (const float*)d_in[9];
    const float* W_hh2 = (const float*)d_in[10];
    const float* b_ih2 = (const float*)d_in[11];
    const float* b_hh2 = (const float*)d_in[12];
    const float* W_out = (const float*)d_in[13];
    const float* b_out = (const float*)d_in[14];
    float* out = (float*)d_out;

    // ---- workspace (~27 MB) ----
    char* ws = (char*)d_ws;
    size_t o = 0;
    const size_t WSZ = (size_t)G3H * H * sizeof(_Float16);
    _Float16* wh1h = (_Float16*)(ws + o); o += WSZ;
    _Float16* wh1l = (_Float16*)(ws + o); o += WSZ;
    _Float16* wi2h = (_Float16*)(ws + o); o += WSZ;
    _Float16* wi2l = (_Float16*)(ws + o); o += WSZ;
    _Float16* wh2h = (_Float16*)(ws + o); o += WSZ;
    _Float16* wh2l = (_Float16*)(ws + o); o += WSZ;
    _Float16 *h1h[2], *h1l[2], *h2h[2], *h2l[2];
    for (int i = 0; i < 2; ++i) { h1h[i] = (_Float16*)(ws + o); o += BHE * 2; }
    for (int i = 0; i < 2; ++i) { h1l[i] = (_Float16*)(ws + o); o += BHE * 2; }
    for (int i = 0; i < 2; ++i) { h2h[i] = (_Float16*)(ws + o); o += BHE * 2; }
    for (int i = 0; i < 2; ++i) { h2l[i] = (_Float16*)(ws + o); o += BHE * 2; }
    float* ypart = (float*)(ws + o); o += (size_t)B * NO * 32 * sizeof(float);

    conv3_kernel<<<(G3H * H + 255) / 256, 256, 0, stream>>>(
        W_hh1, W_ih2, W_hh2, wh1h, wh1l, wi2h, wi2l, wh2h, wh2l);
    prep_kernel<<<(B * H + 255) / 256, 256, 0, stream>>>(
        h01, h02, h1h[0], h1l[0], h2h[0], h2l[0]);

    for (int t = 0; t < T; ++t) {
        const int si = t & 1, so = si ^ 1;

        gru1_kernel<<<512, 512, 0, stream>>>(
            h1h[si], h1l[si], wh1h, wh1l,
            ypart, b_out,
            y0, cmds + (size_t)t * B * NC,
            W_ih1, b_ih1, b_hh1,
            h1h[so], h1l[so],
            out, t);

        gru2_kernel<<<512, 512, 0, stream>>>(
            h1h[so], h1l[so], wi2h, wi2l,
            h2h[si], h2l[si], wh2h, wh2l,
            b_ih2, b_hh2, W_out,
            h2h[so], h2l[so],
            ypart);
    }

    // final y_{T-1}: T even -> final h2 in slot 0
    yout_final_kernel<<<B / 4, 256, 0, stream>>>(
        h2h[0], h2l[0], W_out, b_out, out);
}

// Round 14
// 5988.054 us; speedup vs baseline: 1.0868x; 1.0127x over previous
//
#include <hip/hip_runtime.h>
#include <math.h>

// Problem constants
#define B 2048
#define T 128
#define H 512
#define NC 3
#define NO 5
#define G3H 1536
#define BHE ((size_t)B * H)

typedef _Float16 half8 __attribute__((ext_vector_type(8)));
typedef float float4v __attribute__((ext_vector_type(4)));

#define LO_SCALE 1024.0f
#define INV_LO (1.0f / 1024.0f)
#define F16_MIN_NORM 6.103515625e-05f

__device__ __forceinline__ float sigmoidf_(float x) { return 1.0f / (1.0f + __expf(-x)); }

// Split fp32 -> (hi, lo*1024) f16 pair; hi zeroed in subnormal range (flush safety).
__device__ __forceinline__ void split_f16(float a, _Float16* hi, _Float16* lo) {
    _Float16 h = (_Float16)a;
    if (fabsf(a) < F16_MIN_NORM) h = (_Float16)0.0f;
    *hi = h;
    *lo = (_Float16)((a - (float)h) * LO_SCALE);
}

// element (row,k) of a 512-col matrix stored at row*512 + swzk(row,k):
// 16B chunk c=(k>>3)&7 lives in slot c ^ (row&7)  (LDS-conflict-free fragments)
__device__ __forceinline__ int swzk(int row, int k) {
    return (k & ~63) | ((((k >> 3) & 7) ^ (row & 7)) << 3) | (k & 7);
}
__device__ __forceinline__ size_t hidx(int row, int k) {
    return (size_t)row * H + swzk(row, k);
}

// async 16B global->LDS (wave-uniform LDS base; lane lands at base + lane*16B)
__device__ __forceinline__ void stage16(const _Float16* gp, _Float16* lp) {
    __builtin_amdgcn_global_load_lds(
        (const __attribute__((address_space(1))) unsigned int*)gp,
        (__attribute__((address_space(3))) unsigned int*)lp,
        16, 0, 0);
}

// ---------------- prep kernels (once per launch) ----------------
__global__ void conv3_kernel(const float* __restrict__ w1, const float* __restrict__ w2,
                             const float* __restrict__ w3,
                             _Float16* o1h, _Float16* o1l, _Float16* o2h, _Float16* o2l,
                             _Float16* o3h, _Float16* o3l) {
    int i = blockIdx.x * 256 + threadIdx.x;
    if (i < G3H * H) {
        const int r = i >> 9, k = i & 511;
        const size_t d = (size_t)r * H + swzk(r, k);
        split_f16(w1[i], &o1h[d], &o1l[d]);
        split_f16(w2[i], &o2h[d], &o2l[d]);
        split_f16(w3[i], &o3h[d], &o3l[d]);
    }
}

__global__ void prep_kernel(const float* __restrict__ h01, const float* __restrict__ h02,
                            _Float16* h1h, _Float16* h1l, _Float16* h2h, _Float16* h2l) {
    int i = blockIdx.x * 256 + threadIdx.x;
    if (i < B * H) {
        const int r = i >> 9, k = i & 511;
        const size_t d = (size_t)r * H + swzk(r, k);
        split_f16(h01[i], &h1h[d], &h1l[d]);
        split_f16(h02[i], &h2h[d], &h2l[d]);
    }
}

// ---------------- staging: one 64x64 A-tile + 3-gate 32-col W tile (A 16KB + W 24KB) ----------------
// W chunks: 768 per comp (3 gates x 32 rows x 8 kc). Threads 0-511 -> chunks 0-511 (gates 0,1);
// threads 0-255 (waves 0-3, fully active) -> chunks 512-767 (gate 2).
__device__ __forceinline__ void stage_tile32(
    const _Float16* __restrict__ Ahp, const _Float16* __restrict__ Alp,
    const _Float16* __restrict__ Whp, const _Float16* __restrict__ Wlp,
    int m0, int n0, int k0, int tid, int wv,
    _Float16* sAh, _Float16* sAl, _Float16* sWh, _Float16* sWl)
{
    {
        const int row = tid >> 3, kc = tid & 7;
        const size_t off = (size_t)(m0 + row) * H + k0 + kc * 8;
        stage16(Ahp + off, &sAh[(wv * 64) * 8]);
        stage16(Alp + off, &sAl[(wv * 64) * 8]);
    }
    {
        const int g = tid >> 8, rem = tid & 255;     // gates 0,1
        const int nr = rem >> 3, kc = rem & 7;
        const size_t off = (size_t)(g * H + n0 + nr) * H + k0 + kc * 8;
        stage16(Whp + off, &sWh[(wv * 64) * 8]);
        stage16(Wlp + off, &sWl[(wv * 64) * 8]);
    }
    if (tid < 256) {                                  // gate 2
        const int nr = tid >> 3, kc = tid & 7;
        const size_t off = (size_t)(2 * H + n0 + nr) * H + k0 + kc * 8;
        stage16(Whp + off, &sWh[(512 + wv * 64) * 8]);
        stage16(Wlp + off, &sWl[(512 + wv * 64) * 8]);
    }
}

// ---------------- N=32 compute tile (wave: 16 rows x 16 cols x 3 gates) ----------------
// NS = acc array size; SN = set index for gate 2 (gates 0,1 -> sets 0,1).
template <int SN, int NS>
__device__ __forceinline__ void compute_tile32(
    const _Float16* sAh_, const _Float16* sAl_,
    const _Float16* sWh_, const _Float16* sWl_,
    int wm, int wn, int ln, int qd,
    float4v (&accH)[NS], float4v (&accL)[NS])
{
    #pragma unroll
    for (int ks = 0; ks < 2; ++ks) {
        const int c = ks * 4 + qd;
        const int row = wm * 16 + ln;
        const int ai = row * 64 + ((c ^ (row & 7)) << 3);
        half8 afh = *(const half8*)&sAh_[ai];
        half8 afl = *(const half8*)&sAl_[ai];
        const int nr = wn * 16 + ln;
        #pragma unroll
        for (int g = 0; g < 3; ++g) {
            const int s = (g < 2) ? g : SN;
            const int wi = (g * 32 + nr) * 64 + ((c ^ (nr & 7)) << 3);
            half8 bh = *(const half8*)&sWh_[wi];
            half8 bl = *(const half8*)&sWl_[wi];
            accH[s] = __builtin_amdgcn_mfma_f32_16x16x32_f16(afh, bh, accH[s], 0, 0, 0);
            accL[s] = __builtin_amdgcn_mfma_f32_16x16x32_f16(afh, bl, accL[s], 0, 0, 0);
            accL[s] = __builtin_amdgcn_mfma_f32_16x16x32_f16(afl, bh, accL[s], 0, 0, 0);
        }
    }
}

// ---------------- layer-1 GRU step — N=32, exactly 80KB LDS -> 2 blocks/CU ----------------
// ypart[m][o][ws]: 32 column-slice partials of h2[t-1].Wout^T, written by gru2(t-1).
// All epilogue inputs (y-sum, cmd, W_ih1, biases) handled AFTER the K-loop: nothing
// live across it except the 24-VGPR accumulator.
__global__ __launch_bounds__(512, 4) void gru1_kernel(
    const _Float16* __restrict__ Ah, const _Float16* __restrict__ Al,    // h1 prev swz
    const _Float16* __restrict__ Wh, const _Float16* __restrict__ Wl,    // wh1 swz
    const float* __restrict__ ypart,
    const float* __restrict__ bout,
    const float* __restrict__ y0, const float* __restrict__ cmd_t,
    const float* __restrict__ W_ih1,
    const float* __restrict__ b_ih1, const float* __restrict__ b_hh1,
    _Float16* __restrict__ hnh, _Float16* __restrict__ hnl,
    float* __restrict__ out, int t)
{
    __shared__ _Float16 sAh[2][4096], sAl[2][4096];   // 32 KB
    __shared__ _Float16 sWh[2][6144], sWl[2][6144];   // 48 KB => 80 KB total

    const int tid = threadIdx.x;
    const int wv = tid >> 6, lane = tid & 63;
    const int wm = wv >> 1, wn = wv & 1;
    const int ln = lane & 15, qd = lane >> 4;
    const int n0 = (blockIdx.x & 15) * 32;            // 16 n-groups of 32 cols
    const int m0 = (blockIdx.x >> 4) * 64;

    stage_tile32(Ah, Al, Wh, Wl, m0, n0, 0, tid, wv, sAh[0], sAl[0], sWh[0], sWl[0]);

    float4v accH[3], accL[3];
    #pragma unroll
    for (int s = 0; s < 3; ++s) { accH[s] = (float4v)(0.f); accL[s] = (float4v)(0.f); }

    // ---- K-loop: gh = h1_prev @ W_hh1^T (8 tiles, dbuf); gates R,Z,Nh -> sets 0,1,2 ----
    for (int it = 0; it < 8; ++it) {
        const int buf = it & 1;
        __syncthreads();
        if (it + 1 < 8)
            stage_tile32(Ah, Al, Wh, Wl, m0, n0, (it + 1) * 64, tid, wv,
                         sAh[buf ^ 1], sAl[buf ^ 1], sWh[buf ^ 1], sWl[buf ^ 1]);
        compute_tile32<2, 3>(sAh[buf], sAl[buf], sWh[buf], sWl[buf], wm, wn, ln, qd, accH, accL);
    }

    // ---- sX = [y_{t-1}, cmd_t] on sAh[0] overlay (free: final iteration reads buf 1 only) ----
    float* sX = (float*)&sAh[0][0];   // 64 rows x 8 floats = 2 KB
    const int yr = tid >> 3, yp = tid & 7;   // row, slice-quad
    if (t == 0) {
        if (tid < 64) {
            #pragma unroll
            for (int o2 = 0; o2 < NO; ++o2)
                sX[tid * 8 + o2] = y0[(size_t)(m0 + tid) * NO + o2];
        }
    } else {
        const int row = m0 + yr;
        float a5[NO];
        #pragma unroll
        for (int o2 = 0; o2 < NO; ++o2) {
            const float4 v = *(const float4*)(ypart + ((size_t)row * NO + o2) * 32 + yp * 4);
            a5[o2] = (v.x + v.y) + (v.z + v.w);
        }
        #pragma unroll
        for (int off = 1; off < 8; off <<= 1)
            #pragma unroll
            for (int o2 = 0; o2 < NO; ++o2) a5[o2] += __shfl_xor(a5[o2], off, 64);
        if (yp == 0) {
            #pragma unroll
            for (int o2 = 0; o2 < NO; ++o2) {
                const float y = a5[o2] + bout[o2];
                sX[yr * 8 + o2] = y;
                if (n0 == 0)
                    out[(size_t)(m0 + yr) * (T * NO) + (size_t)(t - 1) * NO + o2] = y;
            }
        }
    }
    if (tid < 64) {
        #pragma unroll
        for (int c = 0; c < NC; ++c)
            sX[tid * 8 + NO + c] = cmd_t[(size_t)(m0 + tid) * NC + c];
    }
    __syncthreads();

    // ---- epilogue: fp32 input path (K=8, W_ih1/biases direct from L2) + gates + blend ----
    const int gnl = wn * 16 + ln;
    const int gn = n0 + gnl;
    float wi[3][8];
    #pragma unroll
    for (int g = 0; g < 3; ++g) {
        const float4 w0 = *(const float4*)(W_ih1 + (size_t)(g * H + gn) * 8);
        const float4 w1 = *(const float4*)(W_ih1 + (size_t)(g * H + gn) * 8 + 4);
        wi[g][0] = w0.x; wi[g][1] = w0.y; wi[g][2] = w0.z; wi[g][3] = w0.w;
        wi[g][4] = w1.x; wi[g][5] = w1.y; wi[g][6] = w1.z; wi[g][7] = w1.w;
    }
    const float bi0 = b_ih1[0 * H + gn], bi1 = b_ih1[1 * H + gn], bi2 = b_ih1[2 * H + gn];
    const float bh0 = b_hh1[0 * H + gn], bh1 = b_hh1[1 * H + gn], bh2 = b_hh1[2 * H + gn];
    #pragma unroll
    for (int r = 0; r < 4; ++r) {
        const int mloc = wm * 16 + qd * 4 + r;
        const int m = m0 + mloc;
        float giR = bi0, giZ = bi1, giN = bi2;
        #pragma unroll
        for (int k = 0; k < 8; ++k) {
            const float xv = sX[mloc * 8 + k];
            giR = fmaf(xv, wi[0][k], giR);
            giZ = fmaf(xv, wi[1][k], giZ);
            giN = fmaf(xv, wi[2][k], giN);
        }
        const float gR = giR + bh0 + accH[0][r] + accL[0][r] * INV_LO;
        const float gZ = giZ + bh1 + accH[1][r] + accL[1][r] * INV_LO;
        const float gNh = bh2 + accH[2][r] + accL[2][r] * INV_LO;
        const float R = sigmoidf_(gR), Z = sigmoidf_(gZ);
        const float N = tanhf(fmaf(R, gNh, giN));
        const size_t idx = hidx(m, gn);
        const float hp = (float)Ah[idx] + (float)Al[idx] * INV_LO;
        const float hv = (1.f - Z) * N + Z * hp;
        split_f16(hv, &hnh[idx], &hnl[idx]);
    }
}

// ---------------- layer-2 GRU step — N=32/80KB/2-block + y-partial emission ----------------
__global__ __launch_bounds__(512, 4) void gru2_kernel(
    const _Float16* __restrict__ Aih, const _Float16* __restrict__ Ail,  // h1 cur swz
    const _Float16* __restrict__ Wih, const _Float16* __restrict__ Wil,  // wi2 swz
    const _Float16* __restrict__ Ahh, const _Float16* __restrict__ Ahl,  // h2 prev swz
    const _Float16* __restrict__ Whh, const _Float16* __restrict__ Whl,  // wh2 swz
    const float* __restrict__ b_i, const float* __restrict__ b_h,
    const float* __restrict__ Wout,
    _Float16* __restrict__ hnh, _Float16* __restrict__ hnl,
    float* __restrict__ ypart)
{
    __shared__ _Float16 sAh[2][4096], sAl[2][4096];   // 64x64 A (16KB + 16KB)
    __shared__ _Float16 sWh[2][6144], sWl[2][6144];   // 3x32x64 W (24KB + 24KB) => 80KB total

    const int tid = threadIdx.x;
    const int wv = tid >> 6, lane = tid & 63;
    const int wm = wv >> 1, wn = wv & 1;
    const int ln = lane & 15, qd = lane >> 4;
    const int n0 = (blockIdx.x & 15) * 32;            // 16 n-groups of 32 cols
    const int m0 = (blockIdx.x >> 4) * 64;

    float4v accH[4], accL[4];
    #pragma unroll
    for (int s = 0; s < 4; ++s) { accH[s] = (float4v)(0.f); accL[s] = (float4v)(0.f); }

    stage_tile32(Aih, Ail, Wih, Wil, m0, n0, 0, tid, wv, sAh[0], sAl[0], sWh[0], sWl[0]);
    for (int it = 0; it < 16; ++it) {
        const int buf = it & 1;
        __syncthreads();
        if (it + 1 < 16) {
            const int k0 = ((it + 1) & 7) * 64;
            if (it + 1 < 8)
                stage_tile32(Aih, Ail, Wih, Wil, m0, n0, k0, tid, wv,
                             sAh[buf ^ 1], sAl[buf ^ 1], sWh[buf ^ 1], sWl[buf ^ 1]);
            else
                stage_tile32(Ahh, Ahl, Whh, Whl, m0, n0, k0, tid, wv,
                             sAh[buf ^ 1], sAl[buf ^ 1], sWh[buf ^ 1], sWl[buf ^ 1]);
        }
        if (it < 8)
            compute_tile32<2, 4>(sAh[buf], sAl[buf], sWh[buf], sWl[buf], wm, wn, ln, qd, accH, accL);
        else
            compute_tile32<3, 4>(sAh[buf], sAl[buf], sWh[buf], sWl[buf], wm, wn, ln, qd, accH, accL);
    }

    // epilogue: biases direct from global; emit per-16-col y partials (no atomics)
    const int gnl = wn * 16 + ln;
    const int gn = n0 + gnl;
    const float bi0 = b_i[0 * H + gn], bi1 = b_i[1 * H + gn], bi2 = b_i[2 * H + gn];
    const float bh0 = b_h[0 * H + gn], bh1 = b_h[1 * H + gn], bh2 = b_h[2 * H + gn];
    const float wo0 = Wout[0 * H + gn], wo1 = Wout[1 * H + gn], wo2 = Wout[2 * H + gn];
    const float wo3 = Wout[3 * H + gn], wo4 = Wout[4 * H + gn];
    const int ws = (blockIdx.x & 15) * 2 + wn;        // 32 column slices of 16
    #pragma unroll
    for (int r = 0; r < 4; ++r) {
        const int m = m0 + wm * 16 + qd * 4 + r;
        const float gR = bi0 + bh0 + accH[0][r] + accL[0][r] * INV_LO;
        const float gZ = bi1 + bh1 + accH[1][r] + accL[1][r] * INV_LO;
        const float gNi = bi2 + accH[2][r] + accL[2][r] * INV_LO;
        const float gNh = bh2 + accH[3][r] + accL[3][r] * INV_LO;
        const float R = sigmoidf_(gR), Z = sigmoidf_(gZ);
        const float N = tanhf(fmaf(R, gNh, gNi));
        const size_t idx = hidx(m, gn);
        const float hp = (float)Ahh[idx] + (float)Ahl[idx] * INV_LO;
        const float hv = (1.f - Z) * N + Z * hp;
        split_f16(hv, &hnh[idx], &hnl[idx]);

        float p0 = hv * wo0, p1 = hv * wo1, p2 = hv * wo2, p3 = hv * wo3, p4 = hv * wo4;
        #pragma unroll
        for (int off = 1; off < 16; off <<= 1) {
            p0 += __shfl_xor(p0, off, 64);
            p1 += __shfl_xor(p1, off, 64);
            p2 += __shfl_xor(p2, off, 64);
            p3 += __shfl_xor(p3, off, 64);
            p4 += __shfl_xor(p4, off, 64);
        }
        if (ln == 0) {
            float* yp = ypart + (size_t)m * NO * 32 + ws;
            yp[0 * 32] = p0;
            yp[1 * 32] = p1;
            yp[2 * 32] = p2;
            yp[3 * 32] = p3;
            yp[4 * 32] = p4;
        }
    }
}

// ---------------- final-step output projection ----------------
__global__ __launch_bounds__(256) void yout_final_kernel(
    const _Float16* __restrict__ h2h, const _Float16* __restrict__ h2l,
    const float* __restrict__ Wout, const float* __restrict__ bout,
    float* __restrict__ out)
{
    const int wv = threadIdx.x >> 6, lane = threadIdx.x & 63;
    const int b = blockIdx.x * 4 + wv;
    const size_t hb = (size_t)b * H + lane * 8;
    half8 hh = *(const half8*)(h2h + hb);
    half8 hl = *(const half8*)(h2l + hb);
    const int tl = lane >> 3, cw = lane & 7;
    const int kbase = tl * 64 + ((cw ^ (b & 7)) << 3);
    float hv[8];
    #pragma unroll
    for (int j = 0; j < 8; ++j) hv[j] = (float)hh[j] + (float)hl[j] * INV_LO;
    float acc[NO];
    #pragma unroll
    for (int o = 0; o < NO; ++o) {
        acc[o] = 0.f;
        const float* w = Wout + (size_t)o * H + kbase;
        #pragma unroll
        for (int j = 0; j < 8; ++j) acc[o] = fmaf(hv[j], w[j], acc[o]);
    }
    #pragma unroll
    for (int off = 32; off > 0; off >>= 1)
        #pragma unroll
        for (int o = 0; o < NO; ++o) acc[o] += __shfl_down(acc[o], off, 64);
    if (lane == 0) {
        #pragma unroll
        for (int o = 0; o < NO; ++o)
            out[(size_t)b * (T * NO) + (size_t)(T - 1) * NO + o] = acc[o] + bout[o];
    }
}

extern "C" void kernel_launch(void* const* d_in, const int* in_sizes, int n_in,
                              void* d_out, int out_size, void* d_ws, size_t ws_size,
                              hipStream_t stream) {
    (void)in_sizes; (void)n_in; (void)out_size; (void)ws_size;
    const float* cmds  = (const float*)d_in[1];
    const float* y0    = (const float*)d_in[2];
    const float* h01   = (const float*)d_in[3];
    const float* h02   = (const float*)d_in[4];
    const float* W_ih1 = (const float*)d_in[5];
    const float* W_hh1 = (const float*)d_in[6];
    const float* b_ih1 = (const float*)d_in[7];
    const float* b_hh1 = (const float*)d_in[8];
    const float* W_ih2 = (const float*)d_in[9];
    const float* W_hh2 = (const float*)d_in[10];
    const float* b_ih2 = (const float*)d_in[11];
    const float* b_hh2 = (const float*)d_in[12];
    const float* W_out = (const float*)d_in[13];
    const float* b_out = (const float*)d_in[14];
    float* out = (float*)d_out;

    // ---- workspace (~27 MB) ----
    char* ws = (char*)d_ws;
    size_t o = 0;
    const size_t WSZ = (size_t)G3H * H * sizeof(_Float16);
    _Float16* wh1h = (_Float16*)(ws + o); o += WSZ;
    _Float16* wh1l = (_Float16*)(ws + o); o += WSZ;
    _Float16* wi2h = (_Float16*)(ws + o); o += WSZ;
    _Float16* wi2l = (_Float16*)(ws + o); o += WSZ;
    _Float16* wh2h = (_Float16*)(ws + o); o += WSZ;
    _Float16* wh2l = (_Float16*)(ws + o); o += WSZ;
    _Float16 *h1h[2], *h1l[2], *h2h[2], *h2l[2];
    for (int i = 0; i < 2; ++i) { h1h[i] = (_Float16*)(ws + o); o += BHE * 2; }
    for (int i = 0; i < 2; ++i) { h1l[i] = (_Float16*)(ws + o); o += BHE * 2; }
    for (int i = 0; i < 2; ++i) { h2h[i] = (_Float16*)(ws + o); o += BHE * 2; }
    for (int i = 0; i < 2; ++i) { h2l[i] = (_Float16*)(ws + o); o += BHE * 2; }
    float* ypart = (float*)(ws + o); o += (size_t)B * NO * 32 * sizeof(float);

    conv3_kernel<<<(G3H * H + 255) / 256, 256, 0, stream>>>(
        W_hh1, W_ih2, W_hh2, wh1h, wh1l, wi2h, wi2l, wh2h, wh2l);
    prep_kernel<<<(B * H + 255) / 256, 256, 0, stream>>>(
        h01, h02, h1h[0], h1l[0], h2h[0], h2l[0]);

    for (int t = 0; t < T; ++t) {
        const int si = t & 1, so = si ^ 1;

        gru1_kernel<<<512, 512, 0, stream>>>(
            h1h[si], h1l[si], wh1h, wh1l,
            ypart, b_out,
            y0, cmds + (size_t)t * B * NC,
            W_ih1, b_ih1, b_hh1,
            h1h[so], h1l[so],
            out, t);

        gru2_kernel<<<512, 512, 0, stream>>>(
            h1h[so], h1l[so], wi2h, wi2l,
            h2h[si], h2l[si], wh2h, wh2l,
            b_ih2, b_hh2, W_out,
            h2h[so], h2l[so],
            ypart);
    }

    // final y_{T-1}: T even -> final h2 in slot 0
    yout_final_kernel<<<B / 4, 256, 0, stream>>>(
        h2h[0], h2l[0], W_out, b_out, out);
}

// Round 15
// 5296.277 us; speedup vs baseline: 1.2288x; 1.1306x over previous
//
#include <hip/hip_runtime.h>
#include <math.h>

// Problem constants
#define B 2048
#define T 128
#define H 512
#define NC 3
#define NO 5
#define G3H 1536
#define BHE ((size_t)B * H)

typedef _Float16 half8 __attribute__((ext_vector_type(8)));
typedef float float4v __attribute__((ext_vector_type(4)));

#define LO_SCALE 1024.0f
#define INV_LO (1.0f / 1024.0f)
#define F16_MIN_NORM 6.103515625e-05f

__device__ __forceinline__ float sigmoidf_(float x) { return 1.0f / (1.0f + __expf(-x)); }

// Split fp32 -> (hi, lo*1024) f16 pair; hi zeroed in subnormal range (flush safety).
__device__ __forceinline__ void split_f16(float a, _Float16* hi, _Float16* lo) {
    _Float16 h = (_Float16)a;
    if (fabsf(a) < F16_MIN_NORM) h = (_Float16)0.0f;
    *hi = h;
    *lo = (_Float16)((a - (float)h) * LO_SCALE);
}

// element (row,k) of a 512-col matrix stored at row*512 + swzk(row,k):
// 16B chunk c=(k>>3)&7 lives in slot c ^ (row&7)  (LDS-conflict-free fragments)
__device__ __forceinline__ int swzk(int row, int k) {
    return (k & ~63) | ((((k >> 3) & 7) ^ (row & 7)) << 3) | (k & 7);
}
__device__ __forceinline__ size_t hidx(int row, int k) {
    return (size_t)row * H + swzk(row, k);
}

// async 16B global->LDS (wave-uniform LDS base; lane lands at base + lane*16B)
__device__ __forceinline__ void stage16(const _Float16* gp, _Float16* lp) {
    __builtin_amdgcn_global_load_lds(
        (const __attribute__((address_space(1))) unsigned int*)gp,
        (__attribute__((address_space(3))) unsigned int*)lp,
        16, 0, 0);
}

// ---------------- prep kernels (once per launch) ----------------
__global__ void conv3_kernel(const float* __restrict__ w1, const float* __restrict__ w2,
                             const float* __restrict__ w3,
                             _Float16* o1h, _Float16* o1l, _Float16* o2h, _Float16* o2l,
                             _Float16* o3h, _Float16* o3l) {
    int i = blockIdx.x * 256 + threadIdx.x;
    if (i < G3H * H) {
        const int r = i >> 9, k = i & 511;
        const size_t d = (size_t)r * H + swzk(r, k);
        split_f16(w1[i], &o1h[d], &o1l[d]);
        split_f16(w2[i], &o2h[d], &o2l[d]);
        split_f16(w3[i], &o3h[d], &o3l[d]);
    }
}

__global__ void prep_kernel(const float* __restrict__ h01, const float* __restrict__ h02,
                            _Float16* h1h, _Float16* h1l, _Float16* h2h, _Float16* h2l) {
    int i = blockIdx.x * 256 + threadIdx.x;
    if (i < B * H) {
        const int r = i >> 9, k = i & 511;
        const size_t d = (size_t)r * H + swzk(r, k);
        split_f16(h01[i], &h1h[d], &h1l[d]);
        split_f16(h02[i], &h2h[d], &h2l[d]);
    }
}

// ---------------- staging: one 64x64 A-tile + 3-gate 32-col W tile (A 16KB + W 24KB) ----------------
// W chunks: 768 per comp (3 gates x 32 rows x 8 kc). Threads 0-511 -> chunks 0-511 (gates 0,1);
// threads 0-255 (waves 0-3, fully active) -> chunks 512-767 (gate 2).
__device__ __forceinline__ void stage_tile32(
    const _Float16* __restrict__ Ahp, const _Float16* __restrict__ Alp,
    const _Float16* __restrict__ Whp, const _Float16* __restrict__ Wlp,
    int m0, int n0, int k0, int tid, int wv,
    _Float16* sAh, _Float16* sAl, _Float16* sWh, _Float16* sWl)
{
    {
        const int row = tid >> 3, kc = tid & 7;
        const size_t off = (size_t)(m0 + row) * H + k0 + kc * 8;
        stage16(Ahp + off, &sAh[(wv * 64) * 8]);
        stage16(Alp + off, &sAl[(wv * 64) * 8]);
    }
    {
        const int g = tid >> 8, rem = tid & 255;     // gates 0,1
        const int nr = rem >> 3, kc = rem & 7;
        const size_t off = (size_t)(g * H + n0 + nr) * H + k0 + kc * 8;
        stage16(Whp + off, &sWh[(wv * 64) * 8]);
        stage16(Wlp + off, &sWl[(wv * 64) * 8]);
    }
    if (tid < 256) {                                  // gate 2
        const int nr = tid >> 3, kc = tid & 7;
        const size_t off = (size_t)(2 * H + n0 + nr) * H + k0 + kc * 8;
        stage16(Whp + off, &sWh[(512 + wv * 64) * 8]);
        stage16(Wlp + off, &sWl[(512 + wv * 64) * 8]);
    }
}

// ---------------- N=32 compute tile (wave: 16 rows x 16 cols x 3 gates) ----------------
// NS = acc array size; SN = set index for gate 2 (gates 0,1 -> sets 0,1).
template <int SN, int NS>
__device__ __forceinline__ void compute_tile32(
    const _Float16* sAh_, const _Float16* sAl_,
    const _Float16* sWh_, const _Float16* sWl_,
    int wm, int wn, int ln, int qd,
    float4v (&accH)[NS], float4v (&accL)[NS])
{
    #pragma unroll
    for (int ks = 0; ks < 2; ++ks) {
        const int c = ks * 4 + qd;
        const int row = wm * 16 + ln;
        const int ai = row * 64 + ((c ^ (row & 7)) << 3);
        half8 afh = *(const half8*)&sAh_[ai];
        half8 afl = *(const half8*)&sAl_[ai];
        const int nr = wn * 16 + ln;
        #pragma unroll
        for (int g = 0; g < 3; ++g) {
            const int s = (g < 2) ? g : SN;
            const int wi = (g * 32 + nr) * 64 + ((c ^ (nr & 7)) << 3);
            half8 bh = *(const half8*)&sWh_[wi];
            half8 bl = *(const half8*)&sWl_[wi];
            accH[s] = __builtin_amdgcn_mfma_f32_16x16x32_f16(afh, bh, accH[s], 0, 0, 0);
            accL[s] = __builtin_amdgcn_mfma_f32_16x16x32_f16(afh, bl, accL[s], 0, 0, 0);
            accL[s] = __builtin_amdgcn_mfma_f32_16x16x32_f16(afl, bh, accL[s], 0, 0, 0);
        }
    }
}

// ---------------- layer-1 GRU step — N=32/80KB/2-block; m0-keyed XCD map ----------------
// Block decode: m0 = (bid&31)*64, n0 = (bid>>5)*32  =>  XCD = bid%8 = f(m0).
// All recurrent traffic (h1/h2/ypart write->read) stays on the writer's XCD L2.
__global__ __launch_bounds__(512, 4) void gru1_kernel(
    const _Float16* __restrict__ Ah, const _Float16* __restrict__ Al,    // h1 prev swz
    const _Float16* __restrict__ Wh, const _Float16* __restrict__ Wl,    // wh1 swz
    const float* __restrict__ ypart,
    const float* __restrict__ bout,
    const float* __restrict__ y0, const float* __restrict__ cmd_t,
    const float* __restrict__ W_ih1,
    const float* __restrict__ b_ih1, const float* __restrict__ b_hh1,
    _Float16* __restrict__ hnh, _Float16* __restrict__ hnl,
    float* __restrict__ out, int t)
{
    __shared__ _Float16 sAh[2][4096], sAl[2][4096];   // 32 KB
    __shared__ _Float16 sWh[2][6144], sWl[2][6144];   // 48 KB => 80 KB total

    const int tid = threadIdx.x;
    const int wv = tid >> 6, lane = tid & 63;
    const int wm = wv >> 1, wn = wv & 1;
    const int ln = lane & 15, qd = lane >> 4;
    const int m0 = (blockIdx.x & 31) * 64;            // XCD-keyed: recurrent state local
    const int n0 = (blockIdx.x >> 5) * 32;

    stage_tile32(Ah, Al, Wh, Wl, m0, n0, 0, tid, wv, sAh[0], sAl[0], sWh[0], sWl[0]);

    float4v accH[3], accL[3];
    #pragma unroll
    for (int s = 0; s < 3; ++s) { accH[s] = (float4v)(0.f); accL[s] = (float4v)(0.f); }

    // ---- K-loop: gh = h1_prev @ W_hh1^T (8 tiles, dbuf); gates R,Z,Nh -> sets 0,1,2 ----
    for (int it = 0; it < 8; ++it) {
        const int buf = it & 1;
        __syncthreads();
        if (it + 1 < 8)
            stage_tile32(Ah, Al, Wh, Wl, m0, n0, (it + 1) * 64, tid, wv,
                         sAh[buf ^ 1], sAl[buf ^ 1], sWh[buf ^ 1], sWl[buf ^ 1]);
        compute_tile32<2, 3>(sAh[buf], sAl[buf], sWh[buf], sWl[buf], wm, wn, ln, qd, accH, accL);
    }

    // ---- sX = [y_{t-1}, cmd_t] on sAh[0] overlay (free: final iteration reads buf 1 only) ----
    float* sX = (float*)&sAh[0][0];   // 64 rows x 8 floats = 2 KB
    const int yr = tid >> 3, yp = tid & 7;   // row, slice-quad
    if (t == 0) {
        if (tid < 64) {
            #pragma unroll
            for (int o2 = 0; o2 < NO; ++o2)
                sX[tid * 8 + o2] = y0[(size_t)(m0 + tid) * NO + o2];
        }
    } else {
        const int row = m0 + yr;
        float a5[NO];
        #pragma unroll
        for (int o2 = 0; o2 < NO; ++o2) {
            const float4 v = *(const float4*)(ypart + ((size_t)row * NO + o2) * 32 + yp * 4);
            a5[o2] = (v.x + v.y) + (v.z + v.w);
        }
        #pragma unroll
        for (int off = 1; off < 8; off <<= 1)
            #pragma unroll
            for (int o2 = 0; o2 < NO; ++o2) a5[o2] += __shfl_xor(a5[o2], off, 64);
        if (yp == 0) {
            #pragma unroll
            for (int o2 = 0; o2 < NO; ++o2) {
                const float y = a5[o2] + bout[o2];
                sX[yr * 8 + o2] = y;
                if (n0 == 0)
                    out[(size_t)(m0 + yr) * (T * NO) + (size_t)(t - 1) * NO + o2] = y;
            }
        }
    }
    if (tid < 64) {
        #pragma unroll
        for (int c = 0; c < NC; ++c)
            sX[tid * 8 + NO + c] = cmd_t[(size_t)(m0 + tid) * NC + c];
    }
    __syncthreads();

    // ---- epilogue: fp32 input path (K=8, W_ih1/biases direct from L2) + gates + blend ----
    const int gnl = wn * 16 + ln;
    const int gn = n0 + gnl;
    float wi[3][8];
    #pragma unroll
    for (int g = 0; g < 3; ++g) {
        const float4 w0 = *(const float4*)(W_ih1 + (size_t)(g * H + gn) * 8);
        const float4 w1 = *(const float4*)(W_ih1 + (size_t)(g * H + gn) * 8 + 4);
        wi[g][0] = w0.x; wi[g][1] = w0.y; wi[g][2] = w0.z; wi[g][3] = w0.w;
        wi[g][4] = w1.x; wi[g][5] = w1.y; wi[g][6] = w1.z; wi[g][7] = w1.w;
    }
    const float bi0 = b_ih1[0 * H + gn], bi1 = b_ih1[1 * H + gn], bi2 = b_ih1[2 * H + gn];
    const float bh0 = b_hh1[0 * H + gn], bh1 = b_hh1[1 * H + gn], bh2 = b_hh1[2 * H + gn];
    #pragma unroll
    for (int r = 0; r < 4; ++r) {
        const int mloc = wm * 16 + qd * 4 + r;
        const int m = m0 + mloc;
        float giR = bi0, giZ = bi1, giN = bi2;
        #pragma unroll
        for (int k = 0; k < 8; ++k) {
            const float xv = sX[mloc * 8 + k];
            giR = fmaf(xv, wi[0][k], giR);
            giZ = fmaf(xv, wi[1][k], giZ);
            giN = fmaf(xv, wi[2][k], giN);
        }
        const float gR = giR + bh0 + accH[0][r] + accL[0][r] * INV_LO;
        const float gZ = giZ + bh1 + accH[1][r] + accL[1][r] * INV_LO;
        const float gNh = bh2 + accH[2][r] + accL[2][r] * INV_LO;
        const float R = sigmoidf_(gR), Z = sigmoidf_(gZ);
        const float N = tanhf(fmaf(R, gNh, giN));
        const size_t idx = hidx(m, gn);
        const float hp = (float)Ah[idx] + (float)Al[idx] * INV_LO;
        const float hv = (1.f - Z) * N + Z * hp;
        split_f16(hv, &hnh[idx], &hnl[idx]);
    }
}

// ---------------- layer-2 GRU step — N=32/80KB/2-block + y-partials; m0-keyed XCD map ----------------
__global__ __launch_bounds__(512, 4) void gru2_kernel(
    const _Float16* __restrict__ Aih, const _Float16* __restrict__ Ail,  // h1 cur swz
    const _Float16* __restrict__ Wih, const _Float16* __restrict__ Wil,  // wi2 swz
    const _Float16* __restrict__ Ahh, const _Float16* __restrict__ Ahl,  // h2 prev swz
    const _Float16* __restrict__ Whh, const _Float16* __restrict__ Whl,  // wh2 swz
    const float* __restrict__ b_i, const float* __restrict__ b_h,
    const float* __restrict__ Wout,
    _Float16* __restrict__ hnh, _Float16* __restrict__ hnl,
    float* __restrict__ ypart)
{
    __shared__ _Float16 sAh[2][4096], sAl[2][4096];   // 64x64 A (16KB + 16KB)
    __shared__ _Float16 sWh[2][6144], sWl[2][6144];   // 3x32x64 W (24KB + 24KB) => 80KB total

    const int tid = threadIdx.x;
    const int wv = tid >> 6, lane = tid & 63;
    const int wm = wv >> 1, wn = wv & 1;
    const int ln = lane & 15, qd = lane >> 4;
    const int m0 = (blockIdx.x & 31) * 64;            // XCD-keyed: recurrent state local
    const int n0 = (blockIdx.x >> 5) * 32;

    float4v accH[4], accL[4];
    #pragma unroll
    for (int s = 0; s < 4; ++s) { accH[s] = (float4v)(0.f); accL[s] = (float4v)(0.f); }

    stage_tile32(Aih, Ail, Wih, Wil, m0, n0, 0, tid, wv, sAh[0], sAl[0], sWh[0], sWl[0]);
    for (int it = 0; it < 16; ++it) {
        const int buf = it & 1;
        __syncthreads();
        if (it + 1 < 16) {
            const int k0 = ((it + 1) & 7) * 64;
            if (it + 1 < 8)
                stage_tile32(Aih, Ail, Wih, Wil, m0, n0, k0, tid, wv,
                             sAh[buf ^ 1], sAl[buf ^ 1], sWh[buf ^ 1], sWl[buf ^ 1]);
            else
                stage_tile32(Ahh, Ahl, Whh, Whl, m0, n0, k0, tid, wv,
                             sAh[buf ^ 1], sAl[buf ^ 1], sWh[buf ^ 1], sWl[buf ^ 1]);
        }
        if (it < 8)
            compute_tile32<2, 4>(sAh[buf], sAl[buf], sWh[buf], sWl[buf], wm, wn, ln, qd, accH, accL);
        else
            compute_tile32<3, 4>(sAh[buf], sAl[buf], sWh[buf], sWl[buf], wm, wn, ln, qd, accH, accL);
    }

    // epilogue: biases direct from global; emit per-16-col y partials (no atomics)
    const int gnl = wn * 16 + ln;
    const int gn = n0 + gnl;
    const float bi0 = b_i[0 * H + gn], bi1 = b_i[1 * H + gn], bi2 = b_i[2 * H + gn];
    const float bh0 = b_h[0 * H + gn], bh1 = b_h[1 * H + gn], bh2 = b_h[2 * H + gn];
    const float wo0 = Wout[0 * H + gn], wo1 = Wout[1 * H + gn], wo2 = Wout[2 * H + gn];
    const float wo3 = Wout[3 * H + gn], wo4 = Wout[4 * H + gn];
    const int ws = (blockIdx.x >> 5) * 2 + wn;        // 32 column slices of 16
    #pragma unroll
    for (int r = 0; r < 4; ++r) {
        const int m = m0 + wm * 16 + qd * 4 + r;
        const float gR = bi0 + bh0 + accH[0][r] + accL[0][r] * INV_LO;
        const float gZ = bi1 + bh1 + accH[1][r] + accL[1][r] * INV_LO;
        const float gNi = bi2 + accH[2][r] + accL[2][r] * INV_LO;
        const float gNh = bh2 + accH[3][r] + accL[3][r] * INV_LO;
        const float R = sigmoidf_(gR), Z = sigmoidf_(gZ);
        const float N = tanhf(fmaf(R, gNh, gNi));
        const size_t idx = hidx(m, gn);
        const float hp = (float)Ahh[idx] + (float)Ahl[idx] * INV_LO;
        const float hv = (1.f - Z) * N + Z * hp;
        split_f16(hv, &hnh[idx], &hnl[idx]);

        float p0 = hv * wo0, p1 = hv * wo1, p2 = hv * wo2, p3 = hv * wo3, p4 = hv * wo4;
        #pragma unroll
        for (int off = 1; off < 16; off <<= 1) {
            p0 += __shfl_xor(p0, off, 64);
            p1 += __shfl_xor(p1, off, 64);
            p2 += __shfl_xor(p2, off, 64);
            p3 += __shfl_xor(p3, off, 64);
            p4 += __shfl_xor(p4, off, 64);
        }
        if (ln == 0) {
            float* yp = ypart + (size_t)m * NO * 32 + ws;
            yp[0 * 32] = p0;
            yp[1 * 32] = p1;
            yp[2 * 32] = p2;
            yp[3 * 32] = p3;
            yp[4 * 32] = p4;
        }
    }
}

// ---------------- final-step output projection ----------------
__global__ __launch_bounds__(256) void yout_final_kernel(
    const _Float16* __restrict__ h2h, const _Float16* __restrict__ h2l,
    const float* __restrict__ Wout, const float* __restrict__ bout,
    float* __restrict__ out)
{
    const int wv = threadIdx.x >> 6, lane = threadIdx.x & 63;
    const int b = blockIdx.x * 4 + wv;
    const size_t hb = (size_t)b * H + lane * 8;
    half8 hh = *(const half8*)(h2h + hb);
    half8 hl = *(const half8*)(h2l + hb);
    const int tl = lane >> 3, cw = lane & 7;
    const int kbase = tl * 64 + ((cw ^ (b & 7)) << 3);
    float hv[8];
    #pragma unroll
    for (int j = 0; j < 8; ++j) hv[j] = (float)hh[j] + (float)hl[j] * INV_LO;
    float acc[NO];
    #pragma unroll
    for (int o = 0; o < NO; ++o) {
        acc[o] = 0.f;
        const float* w = Wout + (size_t)o * H + kbase;
        #pragma unroll
        for (int j = 0; j < 8; ++j) acc[o] = fmaf(hv[j], w[j], acc[o]);
    }
    #pragma unroll
    for (int off = 32; off > 0; off >>= 1)
        #pragma unroll
        for (int o = 0; o < NO; ++o) acc[o] += __shfl_down(acc[o], off, 64);
    if (lane == 0) {
        #pragma unroll
        for (int o = 0; o < NO; ++o)
            out[(size_t)b * (T * NO) + (size_t)(T - 1) * NO + o] = acc[o] + bout[o];
    }
}

extern "C" void kernel_launch(void* const* d_in, const int* in_sizes, int n_in,
                              void* d_out, int out_size, void* d_ws, size_t ws_size,
                              hipStream_t stream) {
    (void)in_sizes; (void)n_in; (void)out_size; (void)ws_size;
    const float* cmds  = (const float*)d_in[1];
    const float* y0    = (const float*)d_in[2];
    const float* h01   = (const float*)d_in[3];
    const float* h02   = (const float*)d_in[4];
    const float* W_ih1 = (const float*)d_in[5];
    const float* W_hh1 = (const float*)d_in[6];
    const float* b_ih1 = (const float*)d_in[7];
    const float* b_hh1 = (const float*)d_in[8];
    const float* W_ih2 = (const float*)d_in[9];
    const float* W_hh2 = (const float*)d_in[10];
    const float* b_ih2 = (const float*)d_in[11];
    const float* b_hh2 = (const float*)d_in[12];
    const float* W_out = (const float*)d_in[13];
    const float* b_out = (const float*)d_in[14];
    float* out = (float*)d_out;

    // ---- workspace (~27 MB) ----
    char* ws = (char*)d_ws;
    size_t o = 0;
    const size_t WSZ = (size_t)G3H * H * sizeof(_Float16);
    _Float16* wh1h = (_Float16*)(ws + o); o += WSZ;
    _Float16* wh1l = (_Float16*)(ws + o); o += WSZ;
    _Float16* wi2h = (_Float16*)(ws + o); o += WSZ;
    _Float16* wi2l = (_Float16*)(ws + o); o += WSZ;
    _Float16* wh2h = (_Float16*)(ws + o); o += WSZ;
    _Float16* wh2l = (_Float16*)(ws + o); o += WSZ;
    _Float16 *h1h[2], *h1l[2], *h2h[2], *h2l[2];
    for (int i = 0; i < 2; ++i) { h1h[i] = (_Float16*)(ws + o); o += BHE * 2; }
    for (int i = 0; i < 2; ++i) { h1l[i] = (_Float16*)(ws + o); o += BHE * 2; }
    for (int i = 0; i < 2; ++i) { h2h[i] = (_Float16*)(ws + o); o += BHE * 2; }
    for (int i = 0; i < 2; ++i) { h2l[i] = (_Float16*)(ws + o); o += BHE * 2; }
    float* ypart = (float*)(ws + o); o += (size_t)B * NO * 32 * sizeof(float);

    conv3_kernel<<<(G3H * H + 255) / 256, 256, 0, stream>>>(
        W_hh1, W_ih2, W_hh2, wh1h, wh1l, wi2h, wi2l, wh2h, wh2l);
    prep_kernel<<<(B * H + 255) / 256, 256, 0, stream>>>(
        h01, h02, h1h[0], h1l[0], h2h[0], h2l[0]);

    for (int t = 0; t < T; ++t) {
        const int si = t & 1, so = si ^ 1;

        gru1_kernel<<<512, 512, 0, stream>>>(
            h1h[si], h1l[si], wh1h, wh1l,
            ypart, b_out,
            y0, cmds + (size_t)t * B * NC,
            W_ih1, b_ih1, b_hh1,
            h1h[so], h1l[so],
            out, t);

        gru2_kernel<<<512, 512, 0, stream>>>(
            h1h[so], h1l[so], wi2h, wi2l,
            h2h[si], h2l[si], wh2h, wh2l,
            b_ih2, b_hh2, W_out,
            h2h[so], h2l[so],
            ypart);
    }

    // final y_{T-1}: T even -> final h2 in slot 0
    yout_final_kernel<<<B / 4, 256, 0, stream>>>(
        h2h[0], h2l[0], W_out, b_out, out);
}